// Round 5
// baseline (132.612 us; speedup 1.0000x reference)
//
#include <hip/hip_runtime.h>
#include <hip/hip_bf16.h>
#include <stdint.h>

#define N_NODES 8192
#define IN_F    256
#define HD      64
#define NH      2
#define MS      8                        // m-splits (column splits)
#define NT      ((N_NODES / MS) / 64)    // 16 m-tiles per block
#define ALPHA   0.2f

typedef __attribute__((ext_vector_type(8))) short bf16x8s;
typedef __attribute__((ext_vector_type(4))) float f32x4;

// ws layout (bytes)
#define OFF_U      0          // u[h][v][256] f32                   : 4 KB
#define OFF_WFRAG  4096       // W frag-order [8][8][64][8] bf16    : 64 KB
#define OFF_F1     69632      // f1[2][8192] f32                    : 64 KB
#define OFF_F2     135168     // f2[2][8192] f32                    : 64 KB
#define OFF_F2MAX  200704     // f2max[2] f32 (+pad)
#define OFF_G2     200960     // g2[2][8192] float2                 : 128 KB
#define OFF_WHB    332032     // Wh frag-order [2][128][2][4][64][8] bf16 : 2 MB
#define OFF_OP     2429184    // O partials [MS][2][8192][64] f32   : 32 MB
#define OFF_LP     35983616   // L partials [MS][2][8192] f32       : 512 KB
#define OFF_MB     36507648   // adj bitmask [8192][32 cb][4] u64   : 8 MB

__device__ __forceinline__ unsigned short f2bf(float x) {
  union { float f; uint32_t u; } c; c.f = x;
  uint32_t r = c.u + 0x7FFFu + ((c.u >> 16) & 1u);   // RNE
  return (unsigned short)(r >> 16);
}
__device__ __forceinline__ short f2bfs(float x) {
  __hip_bfloat16 b = __float2bfloat16(x);
  return __builtin_bit_cast(short, b);
}

// ---------------- kernel 0: pack adj (int32 0/1) -> bitmask, row-linear stream.
// mbits[row][cb][j] (u64): bit l <-> adj[row][cb*256 + 4l + j]
__global__ __launch_bounds__(256) void gat_pack_kernel(const int* __restrict__ adj,
    unsigned long long* __restrict__ mbits)
{
  int w = threadIdx.x >> 6, l = threadIdx.x & 63;
  int r = blockIdx.x * 4 + w;
  const int4* src = (const int4*)(adj + (size_t)r * N_NODES) + l;   // col 4l
  unsigned long long* dst = mbits + (size_t)r * 128;
#pragma unroll 2
  for (int c = 0; c < 32; ++c) {
    int4 v = src[c * 64];                                           // col c*256 + 4l
    unsigned long long b0 = __ballot(v.x > 0);
    unsigned long long b1 = __ballot(v.y > 0);
    unsigned long long b2 = __ballot(v.z > 0);
    unsigned long long b3 = __ballot(v.w > 0);
    if (l == 0) {
      *(ulonglong2*)(dst + c * 4)     = make_ulonglong2(b0, b1);
      *(ulonglong2*)(dst + c * 4 + 2) = make_ulonglong2(b2, b3);
    }
  }
}

// ---------------- kernel 1: u = W·a (f32) + W repacked to B-fragment order (bf16)
__global__ void gat_prep_kernel(const float* __restrict__ W, const float* __restrict__ a,
                                float* __restrict__ u, unsigned short* __restrict__ wfrag)
{
  int idx = blockIdx.x * 256 + threadIdx.x;
  if (idx < 32768) {
    int j = idx & 7, lane = (idx >> 3) & 63, ks = (idx >> 9) & 7, Dt = idx >> 12;
    int k  = ks * 32 + ((lane >> 4) << 3) + j;
    int dp = Dt * 16 + (lane & 15);
    int hh = dp >> 6, d = dp & 63;
    wfrag[idx] = f2bf(W[(size_t)(hh * IN_F + k) * HD + d]);
  } else if (idx < 32768 + NH * 2 * IN_F) {
    int i2 = idx - 32768;
    int i = i2 & 255, v = (i2 >> 8) & 1, h = i2 >> 9;
    const float* Wp = W + (size_t)(h * IN_F + i) * HD;
    const float* ap = a + h * 2 * HD + v * HD;
    float s = 0.f;
    for (int d = 0; d < HD; ++d) s += Wp[d] * ap[d];
    u[(h * 2 + v) * IN_F + i] = s;
  }
}

// ---------------- kernel 2: f1/f2 = h·u, plus per-column exp pairs G1=exp(f2),Ga=exp(a*f2)
__global__ __launch_bounds__(256) void gat_f12_kernel(const float* __restrict__ hmat,
    const float* __restrict__ u, float* __restrict__ f1, float* __restrict__ f2,
    float2* __restrict__ g2)
{
  int n = blockIdx.x * 4 + (threadIdx.x >> 6);
  int l = threadIdx.x & 63;
  float4 hv = *(const float4*)(hmat + (size_t)n * IN_F + l * 4);
  float s[4];
#pragma unroll
  for (int q = 0; q < 4; ++q) {
    float4 uv = *(const float4*)(u + q * IN_F + l * 4);
    s[q] = hv.x * uv.x + hv.y * uv.y + hv.z * uv.z + hv.w * uv.w;
  }
#pragma unroll
  for (int off = 1; off < 64; off <<= 1) {
#pragma unroll
    for (int q = 0; q < 4; ++q) s[q] += __shfl_xor(s[q], off);
  }
  if (l == 0) {
    f1[n] = s[0];           f2[n] = s[1];
    f1[N_NODES + n] = s[2]; f2[N_NODES + n] = s[3];
    g2[n]           = make_float2(__expf(s[1]), __expf(ALPHA * s[1]));
    g2[N_NODES + n] = make_float2(__expf(s[3]), __expf(ALPHA * s[3]));
  }
}

// ---------------- kernel 3: per-head max of f2 (softmax stability bound)
__global__ void gat_f2max_kernel(const float* __restrict__ f2, float* __restrict__ f2m)
{
  int h = blockIdx.x;
  float m = -1e30f;
  for (int i = threadIdx.x; i < N_NODES; i += 256) m = fmaxf(m, f2[h * N_NODES + i]);
#pragma unroll
  for (int off = 1; off < 64; off <<= 1) m = fmaxf(m, __shfl_xor(m, off));
  __shared__ float red[4];
  if ((threadIdx.x & 63) == 0) red[threadIdx.x >> 6] = m;
  __syncthreads();
  if (threadIdx.x == 0) f2m[h] = fmaxf(fmaxf(red[0], red[1]), fmaxf(red[2], red[3]));
}

// ---------------- kernel 4: Wh = h @ W' (bf16 MFMA), epilogue in B-frag order
__global__ __launch_bounds__(256) void gat_wh_kernel(const float* __restrict__ hmat,
    const unsigned short* __restrict__ wfrag, unsigned short* __restrict__ whb)
{
  int tid = threadIdx.x;
  int w = tid >> 6, l = tid & 63;
  int n0 = blockIdx.x * 64;
  int row = n0 + w * 16 + (l & 15);
  f32x4 acc[8] = {};
#pragma unroll
  for (int ks = 0; ks < 8; ++ks) {
    const float* ap = hmat + (size_t)row * IN_F + ks * 32 + ((l >> 4) << 3);
    float av[8];
    *(float4*)&av[0] = *(const float4*)ap;
    *(float4*)&av[4] = *(const float4*)(ap + 4);
    bf16x8s af;
#pragma unroll
    for (int j = 0; j < 8; ++j) af[j] = f2bfs(av[j]);
#pragma unroll
    for (int Dt = 0; Dt < 8; ++Dt) {
      bf16x8s bfv = *(const bf16x8s*)(wfrag + ((size_t)(Dt * 8 + ks) * 64 + l) * 8);
      acc[Dt] = __builtin_amdgcn_mfma_f32_16x16x32_bf16(af, bfv, acc[Dt], 0, 0, 0);
    }
  }
  int Tm = blockIdx.x;
  int s  = w >> 1;
  int lb = ((w & 1) * 2 + ((l >> 4) >> 1)) * 16 + (l & 15);
  int jh = (l >> 4) & 1;
#pragma unroll
  for (int Dt = 0; Dt < 8; ++Dt) {
    int hh = Dt >> 2, D = Dt & 3;
    ushort4 pk;
    pk.x = f2bf(acc[Dt][0]); pk.y = f2bf(acc[Dt][1]);
    pk.z = f2bf(acc[Dt][2]); pk.w = f2bf(acc[Dt][3]);
    size_t off = ((((size_t)(hh * 128 + Tm) * 2 + s) * 4 + D) * 64 + lb) * 8 + jh * 4;
    *(ushort4*)(whb + off) = pk;
  }
}

// ---------------- kernel 5: streaming masked-softmax + PV. Both heads, 2 row-groups,
// adjacency from BITMASK (32 B per row per 256 cols, L2-resident, reg-prefetched).
__global__ __launch_bounds__(256, 2) void gat_attn_kernel(
    const unsigned long long* __restrict__ mbits, const unsigned short* __restrict__ whb,
    const float* __restrict__ f1, const float2* __restrict__ g2,
    const float* __restrict__ f2max, float* __restrict__ Opart, float* __restrict__ Lpart)
{
  int bx = blockIdx.x;                 // grid = 64*MS
  int split = bx & (MS - 1);
  int T = bx >> 3;
  int tid = threadIdx.x;
  int w = tid >> 6, l = tid & 63;
  int n0 = T * 128;
  int rbase = n0 + w * 16 + (l & 15);  // row-group 0; rg1 = rbase+64
  int mbase = split * (N_NODES / MS);
  int koff = (l >> 4) << 3;

  float E1[NH][2], Ea[NH][2];
#pragma unroll
  for (int h = 0; h < NH; ++h)
#pragma unroll
    for (int rg = 0; rg < 2; ++rg) {
      float f1v = f1[h * N_NODES + rbase + rg * 64];
      float tm  = f1v + f2max[h];
      float mrow = fmaxf(tm, ALPHA * tm);
      E1[h][rg] = __expf(f1v - mrow);
      Ea[h][rg] = __expf(ALPHA * f1v - mrow);
    }

  __shared__ float4 gl[2][512];        // 16 KB: G-pairs per head (1024 cols)
  __shared__ uint4  wbuf[1024];        // 16 KB: whb tile, both heads

  {
    const float4* s0 = (const float4*)(g2 + mbase);
    const float4* s1 = (const float4*)(g2 + N_NODES + mbase);
    gl[0][tid] = s0[tid]; gl[0][tid + 256] = s0[tid + 256];
    gl[1][tid] = s1[tid]; gl[1][tid + 256] = s1[tid + 256];
  }

  // mask pointers: per row, 128 u64; our 1024-col slice = 4 cb x (2 ulonglong2)
  int cb0 = mbase >> 8;
  const ulonglong2* mp0 = (const ulonglong2*)mbits + (size_t)rbase * 64 + cb0 * 2;
  const ulonglong2* mp1 = mp0 + (size_t)64 * 64;   // rg1 = rbase + 64

  const uint4* ws0 = (const uint4*)(whb + ((size_t)(mbase >> 6)) * 4096);
  const uint4* ws1 = (const uint4*)(whb + ((size_t)(128 + (mbase >> 6))) * 4096);

  // prologue: mask cur (cb0) + next (cb1), whb tile 0
  ulonglong2 cmA0 = mp0[0], cmA1 = mp0[1], cmB0 = mp1[0], cmB1 = mp1[1];
  ulonglong2 nmA0 = mp0[2], nmA1 = mp0[3], nmB0 = mp1[2], nmB1 = mp1[3];
  uint4 rw0 = ws0[tid], rw1 = ws0[tid + 256];
  uint4 rw2 = ws1[tid], rw3 = ws1[tid + 256];

  f32x4 acc[NH][2][4] = {};
  float lsum[NH][2] = {};

  for (int mt = 0; mt < NT; ++mt) {
    __syncthreads();                   // prev tile's reads done (covers gl at mt=0)
    wbuf[tid]       = rw0; wbuf[tid + 256] = rw1;
    wbuf[tid + 512] = rw2; wbuf[tid + 768] = rw3;
    if (mt + 1 < NT) {                 // issue-early: next whb tile
      const uint4* wp0 = ws0 + (size_t)(mt + 1) * 512;
      const uint4* wp1 = ws1 + (size_t)(mt + 1) * 512;
      rw0 = wp0[tid]; rw1 = wp0[tid + 256];
      rw2 = wp1[tid]; rw3 = wp1[tid + 256];
    }
    if (mt && (mt & 3) == 0) {         // advance mask regs to new 256-col block
      cmA0 = nmA0; cmA1 = nmA1; cmB0 = nmB0; cmB1 = nmB1;
      int cb = (mt >> 2) + 1;
      if (cb < NT / 4) {
        nmA0 = mp0[cb * 2]; nmA1 = mp0[cb * 2 + 1];
        nmB0 = mp1[cb * 2]; nmB1 = mp1[cb * 2 + 1];
      }
    }
    __syncthreads();                   // wbuf visible

    int shbase = ((mt & 3) << 4) + ((l >> 4) << 1);
    bf16x8s afA[NH][2], afB[NH][2];
#pragma unroll
    for (int s = 0; s < 2; ++s) {
      int sh = shbase + s * 8;
      uint32_t t0 = (uint32_t)(cmA0.x >> sh), t1 = (uint32_t)(cmA0.y >> sh);
      uint32_t t2 = (uint32_t)(cmA1.x >> sh), t3 = (uint32_t)(cmA1.y >> sh);
      uint32_t u0 = (uint32_t)(cmB0.x >> sh), u1 = (uint32_t)(cmB0.y >> sh);
      uint32_t u2 = (uint32_t)(cmB1.x >> sh), u3 = (uint32_t)(cmB1.y >> sh);
#pragma unroll
      for (int h = 0; h < NH; ++h) {
        const float4* gp = &gl[h][(mt * 64 + s * 32 + koff) >> 1];
        float psA = 0.f, psB = 0.f;
#pragma unroll
        for (int k = 0; k < 4; ++k) {
          float4 gv = gp[k];
          uint32_t txA = (k & 1) ? t2 : t0, tyA = (k & 1) ? t3 : t1;
          uint32_t txB = (k & 1) ? u2 : u0, tyB = (k & 1) ? u3 : u1;
          int kb = k >> 1;
          float vA0 = fmaxf(E1[h][0] * gv.x, Ea[h][0] * gv.y);
          float vA1 = fmaxf(E1[h][0] * gv.z, Ea[h][0] * gv.w);
          float vB0 = fmaxf(E1[h][1] * gv.x, Ea[h][1] * gv.y);
          float vB1 = fmaxf(E1[h][1] * gv.z, Ea[h][1] * gv.w);
          float pA0 = ((txA >> kb) & 1) ? vA0 : 0.f;
          float pA1 = ((tyA >> kb) & 1) ? vA1 : 0.f;
          float pB0 = ((txB >> kb) & 1) ? vB0 : 0.f;
          float pB1 = ((tyB >> kb) & 1) ? vB1 : 0.f;
          psA += pA0 + pA1;  psB += pB0 + pB1;
          afA[h][s][2 * k] = f2bfs(pA0); afA[h][s][2 * k + 1] = f2bfs(pA1);
          afB[h][s][2 * k] = f2bfs(pB0); afB[h][s][2 * k + 1] = f2bfs(pB1);
        }
        lsum[h][0] += psA; lsum[h][1] += psB;
      }
    }

#pragma unroll
    for (int h = 0; h < NH; ++h) {
      const unsigned short* lb = (const unsigned short*)wbuf + h * 4096;
#pragma unroll
      for (int s = 0; s < 2; ++s)
#pragma unroll
        for (int D = 0; D < 4; ++D) {
          bf16x8s bfv = *(const bf16x8s*)&lb[(s * 4 + D) * 512 + l * 8];
          acc[h][0][D] = __builtin_amdgcn_mfma_f32_16x16x32_bf16(afA[h][s], bfv, acc[h][0][D], 0, 0, 0);
          acc[h][1][D] = __builtin_amdgcn_mfma_f32_16x16x32_bf16(afB[h][s], bfv, acc[h][1][D], 0, 0, 0);
        }
    }
  }

#pragma unroll
  for (int h = 0; h < NH; ++h)
#pragma unroll
    for (int rg = 0; rg < 2; ++rg) {
      float ls = lsum[h][rg];
      ls += __shfl_xor(ls, 16);
      ls += __shfl_xor(ls, 32);
      if (l < 16) Lpart[((size_t)(split * NH + h) << 13) + n0 + rg * 64 + w * 16 + l] = ls;
      float* op = Opart + (size_t)(split * NH + h) * N_NODES * HD;
#pragma unroll
      for (int D = 0; D < 4; ++D)
#pragma unroll
        for (int r = 0; r < 4; ++r) {
          int orow = n0 + rg * 64 + w * 16 + ((l >> 4) << 2) + r;
          op[(size_t)orow * HD + D * 16 + (l & 15)] = acc[h][rg][D][r];
        }
    }
}

// ---------------- kernel 6: combine splits, normalize, ELU, transpose layout
__global__ __launch_bounds__(256) void gat_final_kernel(const float* __restrict__ Opart,
    const float* __restrict__ Lpart, float* __restrict__ out)
{
  int idx = blockIdx.x * 256 + threadIdx.x;
  int n = idx >> 7, c = idx & 127;
  int h = c >> 6, d = c & 63;
  float v = 0.f, ls = 0.f;
#pragma unroll
  for (int sp = 0; sp < MS; ++sp) {
    v  += Opart[((size_t)(sp * NH + h) * N_NODES + n) * HD + d];
    ls += Lpart[(size_t)(sp * NH + h) * N_NODES + n];
  }
  float r = v / fmaxf(ls, 1e-30f);
  out[idx] = (r > 0.f) ? r : (__expf(r) - 1.f);
}

extern "C" void kernel_launch(void* const* d_in, const int* in_sizes, int n_in,
                              void* d_out, int out_size, void* d_ws, size_t ws_size,
                              hipStream_t stream)
{
  const float* hmat = (const float*)d_in[0];
  const int*   adj  = (const int*)d_in[1];
  const float* W    = (const float*)d_in[2];
  const float* a    = (const float*)d_in[3];
  float* out = (float*)d_out;
  char* ws = (char*)d_ws;

  float* u             = (float*)(ws + OFF_U);
  unsigned short* wfrg = (unsigned short*)(ws + OFF_WFRAG);
  float* f1            = (float*)(ws + OFF_F1);
  float* f2            = (float*)(ws + OFF_F2);
  float* f2m           = (float*)(ws + OFF_F2MAX);
  float2* g2           = (float2*)(ws + OFF_G2);
  unsigned short* whb  = (unsigned short*)(ws + OFF_WHB);
  float* Opart         = (float*)(ws + OFF_OP);
  float* Lpart         = (float*)(ws + OFF_LP);
  unsigned long long* mbits = (unsigned long long*)(ws + OFF_MB);

  gat_pack_kernel <<<N_NODES / 4, 256, 0, stream>>>(adj, mbits);
  gat_prep_kernel <<<132, 256, 0, stream>>>(W, a, u, wfrg);
  gat_f12_kernel  <<<N_NODES / 4, 256, 0, stream>>>(hmat, u, f1, f2, g2);
  gat_f2max_kernel<<<NH, 256, 0, stream>>>(f2, f2m);
  gat_wh_kernel   <<<N_NODES / 64, 256, 0, stream>>>(hmat, wfrg, whb);
  gat_attn_kernel <<<64 * MS, 256, 0, stream>>>(mbits, whb, f1, g2, f2m, Opart, Lpart);
  gat_final_kernel<<<out_size / 256, 256, 0, stream>>>(Opart, Lpart, out);
}

// Round 6
// 111.500 us; speedup vs baseline: 1.1893x; 1.1893x over previous
//
#include <hip/hip_runtime.h>
#include <hip/hip_bf16.h>
#include <stdint.h>

#define N_NODES 8192
#define IN_F    256
#define HD      64
#define NH      2
#define MS      8                        // column splits
#define SLICE   1024                     // cols per block
#define CHUNK   512                      // streamed cols per chunk (2 KB/row contiguous)
#define NT      16                       // 64-col tiles per block
#define ALPHA   0.2f

typedef __attribute__((ext_vector_type(8))) short bf16x8s;
typedef __attribute__((ext_vector_type(4))) float f32x4;

// ws layout (bytes)
#define OFF_U      0          // u[h][v][256] f32                   : 4 KB
#define OFF_WFRAG  4096       // W frag-order [8][8][64][8] bf16    : 64 KB
#define OFF_F1     69632      // f1[2][8192] f32                    : 64 KB
#define OFF_F2     135168     // f2[2][8192] f32                    : 64 KB
#define OFF_F2MAX  200704     // f2max[2] f32 (+pad)
#define OFF_G2     200960     // g2[2][8192] float2                 : 128 KB
#define OFF_WHB    332032     // Wh frag-order [2][128][2][4][64][8] bf16 : 2 MB
#define OFF_OP     2429184    // O partials [MS][2][8192][64] f32   : 32 MB
#define OFF_LP     35983616   // L partials [MS][2][8192] f32       : 512 KB

__device__ __forceinline__ unsigned short f2bf(float x) {
  union { float f; uint32_t u; } c; c.f = x;
  uint32_t r = c.u + 0x7FFFu + ((c.u >> 16) & 1u);   // RNE
  return (unsigned short)(r >> 16);
}
__device__ __forceinline__ short f2bfs(float x) {
  __hip_bfloat16 b = __float2bfloat16(x);
  return __builtin_bit_cast(short, b);
}

// ---------------- kernel 1: u = W·a (f32) + W repacked to B-fragment order (bf16)
__global__ void gat_prep_kernel(const float* __restrict__ W, const float* __restrict__ a,
                                float* __restrict__ u, unsigned short* __restrict__ wfrag)
{
  int idx = blockIdx.x * 256 + threadIdx.x;
  if (idx < 32768) {
    int j = idx & 7, lane = (idx >> 3) & 63, ks = (idx >> 9) & 7, Dt = idx >> 12;
    int k  = ks * 32 + ((lane >> 4) << 3) + j;
    int dp = Dt * 16 + (lane & 15);
    int hh = dp >> 6, d = dp & 63;
    wfrag[idx] = f2bf(W[(size_t)(hh * IN_F + k) * HD + d]);
  } else if (idx < 32768 + NH * 2 * IN_F) {
    int i2 = idx - 32768;
    int i = i2 & 255, v = (i2 >> 8) & 1, h = i2 >> 9;
    const float* Wp = W + (size_t)(h * IN_F + i) * HD;
    const float* ap = a + h * 2 * HD + v * HD;
    float s = 0.f;
    for (int d = 0; d < HD; ++d) s += Wp[d] * ap[d];
    u[(h * 2 + v) * IN_F + i] = s;
  }
}

// ---------------- kernel 2: f1/f2 = h·u, plus per-column exp pairs G1=exp(f2),Ga=exp(a*f2)
__global__ __launch_bounds__(256) void gat_f12_kernel(const float* __restrict__ hmat,
    const float* __restrict__ u, float* __restrict__ f1, float* __restrict__ f2,
    float2* __restrict__ g2)
{
  int n = blockIdx.x * 4 + (threadIdx.x >> 6);
  int l = threadIdx.x & 63;
  float4 hv = *(const float4*)(hmat + (size_t)n * IN_F + l * 4);
  float s[4];
#pragma unroll
  for (int q = 0; q < 4; ++q) {
    float4 uv = *(const float4*)(u + q * IN_F + l * 4);
    s[q] = hv.x * uv.x + hv.y * uv.y + hv.z * uv.z + hv.w * uv.w;
  }
#pragma unroll
  for (int off = 1; off < 64; off <<= 1) {
#pragma unroll
    for (int q = 0; q < 4; ++q) s[q] += __shfl_xor(s[q], off);
  }
  if (l == 0) {
    f1[n] = s[0];           f2[n] = s[1];
    f1[N_NODES + n] = s[2]; f2[N_NODES + n] = s[3];
    g2[n]           = make_float2(__expf(s[1]), __expf(ALPHA * s[1]));
    g2[N_NODES + n] = make_float2(__expf(s[3]), __expf(ALPHA * s[3]));
  }
}

// ---------------- kernel 3: per-head max of f2 (softmax stability bound)
__global__ void gat_f2max_kernel(const float* __restrict__ f2, float* __restrict__ f2m)
{
  int h = blockIdx.x;
  float m = -1e30f;
  for (int i = threadIdx.x; i < N_NODES; i += 256) m = fmaxf(m, f2[h * N_NODES + i]);
#pragma unroll
  for (int off = 1; off < 64; off <<= 1) m = fmaxf(m, __shfl_xor(m, off));
  __shared__ float red[4];
  if ((threadIdx.x & 63) == 0) red[threadIdx.x >> 6] = m;
  __syncthreads();
  if (threadIdx.x == 0) f2m[h] = fmaxf(fmaxf(red[0], red[1]), fmaxf(red[2], red[3]));
}

// ---------------- kernel 4: Wh = h @ W' (bf16 MFMA), epilogue in B-frag order
__global__ __launch_bounds__(256) void gat_wh_kernel(const float* __restrict__ hmat,
    const unsigned short* __restrict__ wfrag, unsigned short* __restrict__ whb)
{
  int tid = threadIdx.x;
  int w = tid >> 6, l = tid & 63;
  int n0 = blockIdx.x * 64;
  int row = n0 + w * 16 + (l & 15);
  f32x4 acc[8] = {};
#pragma unroll
  for (int ks = 0; ks < 8; ++ks) {
    const float* ap = hmat + (size_t)row * IN_F + ks * 32 + ((l >> 4) << 3);
    float av[8];
    *(float4*)&av[0] = *(const float4*)ap;
    *(float4*)&av[4] = *(const float4*)(ap + 4);
    bf16x8s af;
#pragma unroll
    for (int j = 0; j < 8; ++j) af[j] = f2bfs(av[j]);
#pragma unroll
    for (int Dt = 0; Dt < 8; ++Dt) {
      bf16x8s bfv = *(const bf16x8s*)(wfrag + ((size_t)(Dt * 8 + ks) * 64 + l) * 8);
      acc[Dt] = __builtin_amdgcn_mfma_f32_16x16x32_bf16(af, bfv, acc[Dt], 0, 0, 0);
    }
  }
  int Tm = blockIdx.x;
  int s  = w >> 1;
  int lb = ((w & 1) * 2 + ((l >> 4) >> 1)) * 16 + (l & 15);
  int jh = (l >> 4) & 1;
#pragma unroll
  for (int Dt = 0; Dt < 8; ++Dt) {
    int hh = Dt >> 2, D = Dt & 3;
    ushort4 pk;
    pk.x = f2bf(acc[Dt][0]); pk.y = f2bf(acc[Dt][1]);
    pk.z = f2bf(acc[Dt][2]); pk.w = f2bf(acc[Dt][3]);
    size_t off = ((((size_t)(hh * 128 + Tm) * 2 + s) * 4 + D) * 64 + lb) * 8 + jh * 4;
    *(ushort4*)(whb + off) = pk;
  }
}

// ---- fused-attn streaming macros: lane-coalesced row-linear adj loads + ballot pack
#define LOADB(dst, b, cb) { \
  const int* _p = abase + (size_t)(w * 32 + (b) * 4) * N_NODES + (cb) + 4 * l; \
  dst##0 = *(const int4*)_p;                  dst##1 = *(const int4*)(_p + 256); \
  dst##2 = *(const int4*)(_p + N_NODES);      dst##3 = *(const int4*)(_p + N_NODES + 256); \
  dst##4 = *(const int4*)(_p + 2 * N_NODES);  dst##5 = *(const int4*)(_p + 2 * N_NODES + 256); \
  dst##6 = *(const int4*)(_p + 3 * N_NODES);  dst##7 = *(const int4*)(_p + 3 * N_NODES + 256); \
}
#define PACKR(v0, v1, rowexpr, buf) { \
  unsigned long long _b0 = __ballot(v0.x > 0), _b1 = __ballot(v0.y > 0); \
  unsigned long long _b2 = __ballot(v0.z > 0), _b3 = __ballot(v0.w > 0); \
  unsigned long long _b4 = __ballot(v1.x > 0), _b5 = __ballot(v1.y > 0); \
  unsigned long long _b6 = __ballot(v1.z > 0), _b7 = __ballot(v1.w > 0); \
  if (l == 0) { \
    ulonglong2* _mp = (ulonglong2*)&maskbuf[buf][rowexpr][0]; \
    _mp[0] = make_ulonglong2(_b0, _b1); _mp[1] = make_ulonglong2(_b2, _b3); \
    _mp[2] = make_ulonglong2(_b4, _b5); _mp[3] = make_ulonglong2(_b6, _b7); \
  } \
}
#define PACKB(src, b, buf) { \
  PACKR(src##0, src##1, w * 32 + (b) * 4 + 0, buf); \
  PACKR(src##2, src##3, w * 32 + (b) * 4 + 1, buf); \
  PACKR(src##4, src##5, w * 32 + (b) * 4 + 2, buf); \
  PACKR(src##6, src##7, w * 32 + (b) * 4 + 3, buf); \
}

// ---------------- kernel 5: FUSED adj-stream + masked-softmax + PV.
// Per block: 128 rows x 1024 cols, both heads. adj read row-contiguously (2 KB/row
// per chunk), ballot-packed to LDS bitmasks (double-buffered); chunk ch+1 streaming
// hides under chunk ch compute. No global mask round-trip.
__global__ __launch_bounds__(256, 2) void gat_attn_kernel(
    const int* __restrict__ adj, const unsigned short* __restrict__ whb,
    const float* __restrict__ f1, const float2* __restrict__ g2,
    const float* __restrict__ f2max, float* __restrict__ Opart, float* __restrict__ Lpart)
{
  int bx = blockIdx.x;                 // grid = 64*MS
  int split = bx & (MS - 1);
  int T = bx >> 3;
  int tid = threadIdx.x;
  int w = tid >> 6, l = tid & 63;
  int n0 = T * 128;
  int rbase = n0 + w * 16 + (l & 15);  // compute rows: rg0; rg1 = +64
  int mbase = split * SLICE;
  int koff = (l >> 4) << 3;

  __shared__ float4 gl[2][512];                      // 16 KB: G-pairs per head
  __shared__ uint4  wbuf[1024];                      // 16 KB: whb tile, both heads
  __shared__ unsigned long long maskbuf[2][128][8];  // 16 KB: adj bitmasks, 2 chunks

  {  // stage G pairs for the whole 1024-col slice
    const float4* s0 = (const float4*)(g2 + mbase);
    const float4* s1 = (const float4*)(g2 + N_NODES + mbase);
    gl[0][tid] = s0[tid]; gl[0][tid + 256] = s0[tid + 256];
    gl[1][tid] = s1[tid]; gl[1][tid + 256] = s1[tid + 256];
  }

  const int* abase = adj + (size_t)n0 * N_NODES + mbase;

  // ---- prologue: stream chunk 0 (128 rows x 2 KB) -> maskbuf[0], 2-deep pipelined
  {
    int4 sA0, sA1, sA2, sA3, sA4, sA5, sA6, sA7;
    int4 sB0, sB1, sB2, sB3, sB4, sB5, sB6, sB7;
    LOADB(sA, 0, 0); LOADB(sB, 1, 0);
    PACKB(sA, 0, 0); LOADB(sA, 2, 0);
    PACKB(sB, 1, 0); LOADB(sB, 3, 0);
    PACKB(sA, 2, 0); LOADB(sA, 4, 0);
    PACKB(sB, 3, 0); LOADB(sB, 5, 0);
    PACKB(sA, 4, 0); LOADB(sA, 6, 0);
    PACKB(sB, 5, 0); LOADB(sB, 7, 0);
    PACKB(sA, 6, 0); PACKB(sB, 7, 0);
  }

  float E1[NH][2], Ea[NH][2];
#pragma unroll
  for (int h = 0; h < NH; ++h)
#pragma unroll
    for (int rg = 0; rg < 2; ++rg) {
      float f1v = f1[h * N_NODES + rbase + rg * 64];
      float tm  = f1v + f2max[h];
      float mrow = fmaxf(tm, ALPHA * tm);
      E1[h][rg] = __expf(f1v - mrow);
      Ea[h][rg] = __expf(ALPHA * f1v - mrow);
    }

  const uint4* ws0 = (const uint4*)(whb + ((size_t)(mbase >> 6)) * 4096);
  const uint4* ws1 = (const uint4*)(whb + ((size_t)(128 + (mbase >> 6))) * 4096);
  uint4 rw0 = ws0[tid], rw1 = ws0[tid + 256];
  uint4 rw2 = ws1[tid], rw3 = ws1[tid + 256];

  f32x4 acc[NH][2][4] = {};
  float lsum[NH][2] = {};
  ulonglong2 cmA0, cmA1, cmB0, cmB1;

  for (int mt = 0; mt < NT; ++mt) {
    int ch = mt >> 3, tc = mt & 7, q = tc & 3, g = tc >> 2;

    __syncthreads();                   // prev iter's wbuf reads done (covers prologue too)
    wbuf[tid]       = rw0; wbuf[tid + 256] = rw1;
    wbuf[tid + 512] = rw2; wbuf[tid + 768] = rw3;
    __syncthreads();                   // wbuf (and, at chunk edge, masks) visible

    // stream chunk 1: issue this iter's 8 row-loads EARLY (hidden under P+MFMA)
    int4 sA0, sA1, sA2, sA3, sA4, sA5, sA6, sA7;
    if (mt < 8) LOADB(sA, tc, CHUNK);

    if (q == 0) {                      // refresh mask regs for this 256-col group
      const ulonglong2* m0 = (const ulonglong2*)&maskbuf[ch][w * 16 + (l & 15)][g * 4];
      cmA0 = m0[0]; cmA1 = m0[1];
      const ulonglong2* m1 = (const ulonglong2*)&maskbuf[ch][w * 16 + 64 + (l & 15)][g * 4];
      cmB0 = m1[0]; cmB1 = m1[1];
    }

    if (mt + 1 < NT) {                 // issue-early: next whb tile
      const uint4* wp0 = ws0 + (size_t)(mt + 1) * 512;
      const uint4* wp1 = ws1 + (size_t)(mt + 1) * 512;
      rw0 = wp0[tid]; rw1 = wp0[tid + 256];
      rw2 = wp1[tid]; rw3 = wp1[tid + 256];
    }

#pragma unroll
    for (int h = 0; h < NH; ++h) {
      bf16x8s afA[2], afB[2];
#pragma unroll
      for (int s = 0; s < 2; ++s) {
        int sh = (q << 4) + ((l >> 4) << 1) + (s << 3);
        uint32_t t0 = (uint32_t)(cmA0.x >> sh), t1 = (uint32_t)(cmA0.y >> sh);
        uint32_t t2 = (uint32_t)(cmA1.x >> sh), t3 = (uint32_t)(cmA1.y >> sh);
        uint32_t u0 = (uint32_t)(cmB0.x >> sh), u1 = (uint32_t)(cmB0.y >> sh);
        uint32_t u2 = (uint32_t)(cmB1.x >> sh), u3 = (uint32_t)(cmB1.y >> sh);
        const float4* gp = &gl[h][(mt * 64 + s * 32 + koff) >> 1];
        float psA = 0.f, psB = 0.f;
#pragma unroll
        for (int k = 0; k < 4; ++k) {
          float4 gv = gp[k];
          uint32_t txA = (k & 1) ? t2 : t0, tyA = (k & 1) ? t3 : t1;
          uint32_t txB = (k & 1) ? u2 : u0, tyB = (k & 1) ? u3 : u1;
          int kb = k >> 1;
          float vA0 = fmaxf(E1[h][0] * gv.x, Ea[h][0] * gv.y);
          float vA1 = fmaxf(E1[h][0] * gv.z, Ea[h][0] * gv.w);
          float vB0 = fmaxf(E1[h][1] * gv.x, Ea[h][1] * gv.y);
          float vB1 = fmaxf(E1[h][1] * gv.z, Ea[h][1] * gv.w);
          float pA0 = ((txA >> kb) & 1) ? vA0 : 0.f;
          float pA1 = ((tyA >> kb) & 1) ? vA1 : 0.f;
          float pB0 = ((txB >> kb) & 1) ? vB0 : 0.f;
          float pB1 = ((tyB >> kb) & 1) ? vB1 : 0.f;
          psA += pA0 + pA1;  psB += pB0 + pB1;
          afA[s][2 * k] = f2bfs(pA0); afA[s][2 * k + 1] = f2bfs(pA1);
          afB[s][2 * k] = f2bfs(pB0); afB[s][2 * k + 1] = f2bfs(pB1);
        }
        lsum[h][0] += psA; lsum[h][1] += psB;
      }
      const unsigned short* lb = (const unsigned short*)wbuf + h * 4096;
#pragma unroll
      for (int s = 0; s < 2; ++s)
#pragma unroll
        for (int D = 0; D < 4; ++D) {
          bf16x8s bfv = *(const bf16x8s*)&lb[(s * 4 + D) * 512 + l * 8];
          acc[h][0][D] = __builtin_amdgcn_mfma_f32_16x16x32_bf16(afA[s], bfv, acc[h][0][D], 0, 0, 0);
          acc[h][1][D] = __builtin_amdgcn_mfma_f32_16x16x32_bf16(afB[s], bfv, acc[h][1][D], 0, 0, 0);
        }
    }

    // ballot-pack the streamed batch into the other mask buffer (chunk 1)
    if (mt < 8) PACKB(sA, tc, 1);
  }

#pragma unroll
  for (int h = 0; h < NH; ++h)
#pragma unroll
    for (int rg = 0; rg < 2; ++rg) {
      float ls = lsum[h][rg];
      ls += __shfl_xor(ls, 16);
      ls += __shfl_xor(ls, 32);
      if (l < 16) Lpart[((size_t)(split * NH + h) << 13) + n0 + rg * 64 + w * 16 + l] = ls;
      float* op = Opart + (size_t)(split * NH + h) * N_NODES * HD;
#pragma unroll
      for (int D = 0; D < 4; ++D)
#pragma unroll
        for (int r = 0; r < 4; ++r) {
          int orow = n0 + rg * 64 + w * 16 + ((l >> 4) << 2) + r;
          op[(size_t)orow * HD + D * 16 + (l & 15)] = acc[h][rg][D][r];
        }
    }
}

// ---------------- kernel 6: combine splits, normalize, ELU, transpose layout
__global__ __launch_bounds__(256) void gat_final_kernel(const float* __restrict__ Opart,
    const float* __restrict__ Lpart, float* __restrict__ out)
{
  int idx = blockIdx.x * 256 + threadIdx.x;
  int n = idx >> 7, c = idx & 127;
  int h = c >> 6, d = c & 63;
  float v = 0.f, ls = 0.f;
#pragma unroll
  for (int sp = 0; sp < MS; ++sp) {
    v  += Opart[((size_t)(sp * NH + h) * N_NODES + n) * HD + d];
    ls += Lpart[(size_t)(sp * NH + h) * N_NODES + n];
  }
  float r = v / fmaxf(ls, 1e-30f);
  out[idx] = (r > 0.f) ? r : (__expf(r) - 1.f);
}

extern "C" void kernel_launch(void* const* d_in, const int* in_sizes, int n_in,
                              void* d_out, int out_size, void* d_ws, size_t ws_size,
                              hipStream_t stream)
{
  const float* hmat = (const float*)d_in[0];
  const int*   adj  = (const int*)d_in[1];
  const float* W    = (const float*)d_in[2];
  const float* a    = (const float*)d_in[3];
  float* out = (float*)d_out;
  char* ws = (char*)d_ws;

  float* u             = (float*)(ws + OFF_U);
  unsigned short* wfrg = (unsigned short*)(ws + OFF_WFRAG);
  float* f1            = (float*)(ws + OFF_F1);
  float* f2            = (float*)(ws + OFF_F2);
  float* f2m           = (float*)(ws + OFF_F2MAX);
  float2* g2           = (float2*)(ws + OFF_G2);
  unsigned short* whb  = (unsigned short*)(ws + OFF_WHB);
  float* Opart         = (float*)(ws + OFF_OP);
  float* Lpart         = (float*)(ws + OFF_LP);

  gat_prep_kernel <<<132, 256, 0, stream>>>(W, a, u, wfrg);
  gat_f12_kernel  <<<N_NODES / 4, 256, 0, stream>>>(hmat, u, f1, f2, g2);
  gat_f2max_kernel<<<NH, 256, 0, stream>>>(f2, f2m);
  gat_wh_kernel   <<<N_NODES / 64, 256, 0, stream>>>(hmat, wfrg, whb);
  gat_attn_kernel <<<64 * MS, 256, 0, stream>>>(adj, whb, f1, g2, f2m, Opart, Lpart);
  gat_final_kernel<<<out_size / 256, 256, 0, stream>>>(Opart, Lpart, out);
}